// Round 4
// baseline (240.649 us; speedup 1.0000x reference)
//
#include <hip/hip_runtime.h>

constexpr int Tt = 384;   // timesteps
constexpr int Cc = 96;    // classes (blank = 95)
constexpr int Ll = 48;    // max label length
constexpr int Gg = 8;     // rows per group (= rescale period)
constexpr int NG = 24;    // groups per direction (24*8 = 192)
constexpr int GPW = 6;    // groups per wave in phase 1 (48 total / 8 waves)
constexpr int RS = 50;    // LDS row stride: pl lanes 0..48, pb at 49
constexpr int DSZ = NG * Gg * RS;   // 9600 floats per direction
constexpr int PAD = 16;   // finite-junk pad for lane>=50 overreads on last row

#define L2E 1.4426950408889634f
#define LN2 0.6931471805599453f
#define LNEG (-3.0e38f)

// ---- DPP helpers (VALU pipe) ----
template <int CTRL, int RM = 0xF>
__device__ __forceinline__ float dppf(float x) {
    return __int_as_float(
        __builtin_amdgcn_update_dpp(0, __float_as_int(x), CTRL, RM, 0xF, true));
}
template <int CTRL>
__device__ __forceinline__ int dppi(int x) {
    return __builtin_amdgcn_update_dpp(0, x, CTRL, 0xF, 0xF, true);
}
__device__ __forceinline__ float bcast63(float x) {
    return __int_as_float(__builtin_amdgcn_readlane(__float_as_int(x), 63));
}
// full-wave sum of non-negative values, result broadcast
__device__ __forceinline__ float wsum(float x) {
    x += dppf<0x111>(x);          // row_shr:1
    x += dppf<0x112>(x);          // row_shr:2
    x += dppf<0x114>(x);          // row_shr:4
    x += dppf<0x118>(x);          // row_shr:8
    x += dppf<0x142, 0xA>(x);     // row_bcast:15 -> rows 1,3
    x += dppf<0x143, 0xC>(x);     // row_bcast:31 -> rows 2,3
    return bcast63(x);
}
__device__ __forceinline__ float shup1(float x) { return dppf<0x138>(x); } // lane i <- i-1, 0 into lane 0
__device__ __forceinline__ float shdn1(float x) { return dppf<0x130>(x); } // lane i <- i+1, 0 into lane 63
__device__ __forceinline__ float exp2i(int d) {  // 2^d, clamped to fp32-normal range
    d = d < -126 ? -126 : (d > 126 ? 126 : d);
    return __int_as_float((d + 127) << 23);
}

// ---- load one 8-row group of logits (dir is wave-uniform) ----
__device__ __forceinline__ void load_group(const float2* __restrict__ rp2, float2* q,
                                           int dir, int g, int lane) {
#pragma unroll
    for (int j = 0; j < Gg; ++j) {
        int k = g * Gg + j;
        int t = dir ? (Tt - 1 - k) : k;
        q[j] = (lane < 48) ? rp2[(size_t)t * 48 + lane] : make_float2(-1e4f, -1e4f);
    }
}

// ---- softmax one group + store gathered row to LDS (verified arithmetic) ----
// dst row layout: [0..48] = p(label_lane) (48 = finite junk), [49] = p(blank).
__device__ __forceinline__ void sm_store(const float2* q, float* dst, int lane,
                                         int idx_h, int bitsel) {
#pragma unroll
    for (int j = 0; j < Gg; ++j) {
        float ex = __builtin_amdgcn_exp2f(q[j].x * L2E);   // lanes>=48: exp2(-14427) = 0
        float ey = __builtin_amdgcn_exp2f(q[j].y * L2E);
        float gb = __shfl(ey, 47, 64);      // class 95 (blank) -> readlane
        float g0 = __shfl(ex, idx_h, 64);   // class 2*idx_h    -> bpermute
        float g1 = __shfl(ey, idx_h, 64);   // class 2*idx_h+1  -> bpermute
        float s  = wsum(ex + ey);
        float rZ = __builtin_amdgcn_rcpf(s);
        float pl = (bitsel ? g1 : g0) * rZ;
        float pb = gb * rZ;
        if (lane < RS) dst[j * RS + lane] = (lane == 49) ? pb : pl;
    }
}

// ---- one 8-step DP group from LDS, linear space, per-lane exponent ----
template <bool FWD>
__device__ __forceinline__ void dp_group(const float* __restrict__ pr, int lane,
                                         float allow2f, float& st_e, float& st_o,
                                         int& ls, float& f, float& a2f) {
    float plC[Gg], pbC[Gg];
#pragma unroll
    for (int j = 0; j < Gg; ++j) {
        plC[j] = pr[j * RS + lane];   // stride-50 lane read: 2-way bank alias (free)
        pbC[j] = pr[j * RS + 49];     // uniform address -> LDS broadcast
    }
#pragma unroll
    for (int j = 0; j < Gg; ++j) {
        if (FWD) {
            float sh = shup1(st_o);                      // alpha(2i-1), lane i-1 scale
            float t0 = st_e + st_o;
            float ne = fmaf(f, sh, st_e) * pbC[j];
            float no = fmaf(a2f, sh, t0) * plC[j];
            st_e = ne; st_o = no;
        } else {
            float en = shdn1(st_e);                      // beta(2i+2)
            float on = shdn1(st_o);                      // beta(2i+3)
            float ne = (st_e + st_o) * pbC[j];
            float no = fmaf(a2f, on, fmaf(f, en, st_o)) * plC[j];
            st_e = ne; st_o = no;
        }
    }
    // per-lane exact power-of-2 rescale
    float m = fmaxf(st_e, st_o);
    bool z  = (m == 0.0f);
    int eb  = (__float_as_int(m) >> 23) & 0xFF;
    eb = eb > 253 ? 253 : eb;
    float r = z ? 1.0f : __int_as_float((254 - eb) << 23);   // 2^(127-eb), exact
    st_e *= r; st_o *= r;
    ls += z ? 0 : (eb - 127);
    // exponent adoption for zero lanes (front moves <= 8 lanes/group)
#pragma unroll
    for (int it = 0; it < 8; ++it) {
        int lsn = FWD ? dppi<0x138>(ls) : dppi<0x130>(ls);
        ls = z ? lsn : ls;
    }
    int lsn2 = FWD ? dppi<0x138>(ls) : dppi<0x130>(ls);
    f   = exp2i(lsn2 - ls);
    a2f = allow2f * f;
}

__global__ __launch_bounds__(64) void zero_kernel(float* o) { *o = 0.0f; }

// 8 waves/block, 1 batch element/block.
// Phase 1: wave w softmaxes groups [6w, 6w+6) of 48 (0-23 fwd t=0..191, 24-47 bwd
//          t=383..192) into LDS. One barrier.
// Phase 2: wave 0 = full fwd DP, wave 1 = full bwd DP, then combine at t=192.
__global__ __launch_bounds__(512, 4) void ctc_fb(const int* __restrict__ labels,
                                                 const float* __restrict__ pred,
                                                 float* __restrict__ out,
                                                 float invB) {
    const int b    = blockIdx.x;
    const int lane = threadIdx.x & 63;
    const int wv   = threadIdx.x >> 6;
    const float2* rp2 = (const float2*)(pred + (size_t)b * Tt * Cc);

    __shared__ float plb[2][DSZ + PAD];   // ~77 KB
    __shared__ float sbe[64], sbo[64];
    __shared__ int   slsb[64];

    // lane i holds label i (every wave computes identically)
    int v = (lane < Ll) ? labels[(size_t)b * Ll + lane] : -1;
    int present = (lane < Ll) && (v != -1);
    int labv = (v < 0) ? 0 : v;
    unsigned long long pm = __ballot(present);
    int len = __popcll(pm);
    int idx_h  = labv >> 1;
    int bitsel = labv & 1;
    int lab_p = __shfl(labv, (lane - 1) & 63, 64);
    int lab_n = __shfl(labv, (lane + 1) & 63, 64);

    // zero the finite-junk pads (consumed only as multiply-by-zero junk)
    if (threadIdx.x < 2 * PAD) {
        int d = threadIdx.x / PAD, i = threadIdx.x % PAD;
        plb[d][DSZ + i] = 0.0f;
    }

    // ---- phase 1: burst-load + softmax this wave's 6 groups ----
    {
        const int ag0 = GPW * wv;                 // absolute group base
        const int dir = (ag0 >= NG) ? 1 : 0;
        const int g0  = ag0 - dir * NG;           // local group base
        float2 q0[Gg], q1[Gg];
        load_group(rp2, q0, dir, g0 + 0, lane);
        load_group(rp2, q1, dir, g0 + 1, lane);
#pragma unroll
        for (int i = 0; i < GPW; ++i) {
            if ((i & 1) == 0) {
                sm_store(q0, &plb[dir][(g0 + i) * Gg * RS], lane, idx_h, bitsel);
                if (i + 2 < GPW) load_group(rp2, q0, dir, g0 + i + 2, lane);
            } else {
                sm_store(q1, &plb[dir][(g0 + i) * Gg * RS], lane, idx_h, bitsel);
                if (i + 2 < GPW) load_group(rp2, q1, dir, g0 + i + 2, lane);
            }
        }
    }
    __syncthreads();

    // ---- phase 2: serial DP (waves 0,1), others idle at barrier ----
    float st_e = 0.0f, st_o = 0.0f, f = 1.0f, a2f = 0.0f, allow2f = 0.0f;
    int   ls = 0;
    if (wv == 0) {            // fwd DP: virtual pre-start state at lane 0
        allow2f = (lane >= 1 && labv != lab_p) ? 1.0f : 0.0f;
        st_e = (lane == 0) ? 1.0f : 0.0f;
        a2f = allow2f;
        for (int g = 0; g < NG; ++g)
            dp_group<true>(&plb[0][g * Gg * RS], lane, allow2f, st_e, st_o, ls, f, a2f);
    } else if (wv == 1) {     // bwd DP: virtual post-end state at lane == len
        allow2f = (labv != lab_n) ? 1.0f : 0.0f;
        st_e = (lane == len) ? 1.0f : 0.0f;
        a2f = allow2f;
        for (int g = 0; g < NG; ++g)
            dp_group<false>(&plb[1][g * Gg * RS], lane, allow2f, st_e, st_o, ls, f, a2f);
        sbe[lane]  = st_e;
        sbo[lane]  = st_o;
        slsb[lane] = ls;
    }
    __syncthreads();

    if (wv == 0) {
        // transition half-step (no emission) to meet beta at t = 192
        float sh  = shup1(st_o);
        int   lsu = dppi<0x138>(ls);
        float fup = exp2i(lsu - ls);
        float Ae = fmaf(fup, sh, st_e);
        float Ao = fmaf(allow2f * fup, sh, st_e + st_o);
        // combine in log2 domain with integer exponents restored
        float be = sbe[lane], bo = sbo[lane];
        float base = (float)(ls + slsb[lane]);
        float l1 = (Ae > 0.0f && be > 0.0f) ? __log2f(Ae) + __log2f(be) + base : LNEG;
        float l2 = (Ao > 0.0f && bo > 0.0f) ? __log2f(Ao) + __log2f(bo) + base : LNEG;
        float mm = fmaxf(l1, l2);
#pragma unroll
        for (int off = 32; off >= 1; off >>= 1) mm = fmaxf(mm, __shfl_xor(mm, off, 64));
        float ss = exp2f(l1 - mm) + exp2f(l2 - mm);
#pragma unroll
        for (int off = 32; off >= 1; off >>= 1) ss += __shfl_xor(ss, off, 64);
        if (lane == 0) {
            float ll = (mm + __log2f(ss)) * LN2;
            atomicAdd(out, -ll * invB);
        }
    }
}

extern "C" void kernel_launch(void* const* d_in, const int* in_sizes, int n_in,
                              void* d_out, int out_size, void* d_ws, size_t ws_size,
                              hipStream_t stream) {
    const int*   labels = (const int*)d_in[0];
    const float* pred   = (const float*)d_in[1];
    float*       out    = (float*)d_out;

    const int B = in_sizes[0] / Ll;  // 1024

    hipLaunchKernelGGL(zero_kernel, dim3(1), dim3(64), 0, stream, out);
    hipLaunchKernelGGL(ctc_fb, dim3(B), dim3(512), 0, stream,
                       labels, pred, out, 1.0f / (float)B);
}

// Round 5
// 225.212 us; speedup vs baseline: 1.0685x; 1.0685x over previous
//
#include <hip/hip_runtime.h>

constexpr int Tt = 384;   // timesteps
constexpr int Cc = 96;    // classes (blank = 95)
constexpr int Ll = 48;    // max label length
constexpr int Gg = 8;     // rows per group (= rescale period)
constexpr int NG = 24;    // groups per half (24*8 = 192)

#define L2E 1.4426950408889634f
#define LN2 0.6931471805599453f
#define LNEG (-3.0e38f)

// ---- DPP helpers (VALU pipe) ----
template <int CTRL, int RM = 0xF>
__device__ __forceinline__ float dppf(float x) {
    return __int_as_float(
        __builtin_amdgcn_update_dpp(0, __float_as_int(x), CTRL, RM, 0xF, true));
}
template <int CTRL>
__device__ __forceinline__ int dppi(int x) {
    return __builtin_amdgcn_update_dpp(0, x, CTRL, 0xF, 0xF, true);
}
__device__ __forceinline__ float bcast63(float x) {
    return __int_as_float(__builtin_amdgcn_readlane(__float_as_int(x), 63));
}
// full-wave sum of non-negative values, result broadcast
__device__ __forceinline__ float wsum(float x) {
    x += dppf<0x111>(x);          // row_shr:1
    x += dppf<0x112>(x);          // row_shr:2
    x += dppf<0x114>(x);          // row_shr:4
    x += dppf<0x118>(x);          // row_shr:8
    x += dppf<0x142, 0xA>(x);     // row_bcast:15 -> rows 1,3
    x += dppf<0x143, 0xC>(x);     // row_bcast:31 -> rows 2,3
    return bcast63(x);
}
__device__ __forceinline__ float shup1(float x) { return dppf<0x138>(x); } // lane i <- i-1, 0 into lane 0
__device__ __forceinline__ float shdn1(float x) { return dppf<0x130>(x); } // lane i <- i+1, 0 into lane 63
__device__ __forceinline__ float exp2i(int d) {  // 2^d, clamped to fp32-normal range
    d = d < -126 ? -126 : (d > 126 ? 126 : d);
    return __int_as_float((d + 127) << 23);
}

// ---- load one 8-row group of logits ----
template <bool FWD>
__device__ __forceinline__ void prod_load(const float2* __restrict__ rp2, float2* q,
                                          int g, int lane) {
#pragma unroll
    for (int j = 0; j < Gg; ++j) {
        int k = g * Gg + j;
        int t = FWD ? k : (Tt - 1 - k);
        q[j] = (lane < 48) ? rp2[(size_t)t * 48 + lane] : make_float2(-1e4f, -1e4f);
    }
}

// ---- in-wave softmax + gather for one 8-row group (verified arithmetic) ----
__device__ __forceinline__ void softmax_group(const float2* q, float* pl, float* pb,
                                              int idx_h, int bitsel) {
#pragma unroll
    for (int j = 0; j < Gg; ++j) {
        float ex = __builtin_amdgcn_exp2f(q[j].x * L2E);   // lanes>=48: exp2(-14427) = 0
        float ey = __builtin_amdgcn_exp2f(q[j].y * L2E);
        float gb = __shfl(ey, 47, 64);      // class 95 (blank) -> readlane
        float g0 = __shfl(ex, idx_h, 64);   // class 2*idx_h    -> bpermute
        float g1 = __shfl(ey, idx_h, 64);   // class 2*idx_h+1  -> bpermute
        float s  = wsum(ex + ey);
        float rZ = __builtin_amdgcn_rcpf(s);
        pl[j] = (bitsel ? g1 : g0) * rZ;
        pb[j] = gb * rZ;
    }
}

// ---- one 8-step DP group, linear space, per-lane exponent (verified) ----
template <bool FWD>
__device__ __forceinline__ void dp_group(const float* pl, const float* pb,
                                         float allow2f, float& st_e, float& st_o,
                                         int& ls, float& f, float& a2f) {
#pragma unroll
    for (int j = 0; j < Gg; ++j) {
        if (FWD) {
            float sh = shup1(st_o);                      // alpha(2i-1), lane i-1 scale
            float t0 = st_e + st_o;
            float ne = fmaf(f, sh, st_e) * pb[j];
            float no = fmaf(a2f, sh, t0) * pl[j];
            st_e = ne; st_o = no;
        } else {
            float en = shdn1(st_e);                      // beta(2i+2)
            float on = shdn1(st_o);                      // beta(2i+3)
            float ne = (st_e + st_o) * pb[j];
            float no = fmaf(a2f, on, fmaf(f, en, st_o)) * pl[j];
            st_e = ne; st_o = no;
        }
    }
    // per-lane exact power-of-2 rescale
    float m = fmaxf(st_e, st_o);
    bool z  = (m == 0.0f);
    int eb  = (__float_as_int(m) >> 23) & 0xFF;
    eb = eb > 253 ? 253 : eb;
    float r = z ? 1.0f : __int_as_float((254 - eb) << 23);   // 2^(127-eb), exact
    st_e *= r; st_o *= r;
    ls += z ? 0 : (eb - 127);
    // exponent adoption for zero lanes (front moves <= 8 lanes/group)
#pragma unroll
    for (int it = 0; it < 8; ++it) {
        int lsn = FWD ? dppi<0x138>(ls) : dppi<0x130>(ls);
        ls = z ? lsn : ls;
    }
    int lsn2 = FWD ? dppi<0x138>(ls) : dppi<0x130>(ls);
    f   = exp2i(lsn2 - ls);
    a2f = allow2f * f;
}

// ---- self-contained half: 4-deep static load pipeline, softmax 1 group ahead ----
// Load(g) issued 4 groups before softmax(g); softmax(g) one group before dp(g).
// All buffer indices compile-time (inner unroll) -> registers, no scratch.
template <bool FWD>
__device__ __forceinline__ void run_half(const float2* __restrict__ rp2, int lane,
                                         int idx_h, int bitsel, float allow2f,
                                         float& st_e, float& st_o, int& ls,
                                         float& f, float& a2f) {
    float2 q0[Gg], q1[Gg], q2[Gg], q3[Gg];
    float plA[Gg], pbA[Gg], plB[Gg], pbB[Gg];
    prod_load<FWD>(rp2, q0, 0, lane);
    prod_load<FWD>(rp2, q1, 1, lane);
    prod_load<FWD>(rp2, q2, 2, lane);
    prod_load<FWD>(rp2, q3, 3, lane);
    softmax_group(q0, plA, pbA, idx_h, bitsel);               // group 0 -> A
    for (int g4 = 0; g4 < 5; ++g4) {      // groups 4*g4 .. 4*g4+3 ; loads for +4..+7
        int gb = g4 * 4;
        // j = 0: dp(gb+0) [A], softmax(gb+1)->B, load(gb+4)->q0
        prod_load<FWD>(rp2, q0, gb + 4, lane);
        softmax_group(q1, plB, pbB, idx_h, bitsel);
        dp_group<FWD>(plA, pbA, allow2f, st_e, st_o, ls, f, a2f);
        // j = 1: dp(gb+1) [B], softmax(gb+2)->A, load(gb+5)->q1
        prod_load<FWD>(rp2, q1, gb + 5, lane);
        softmax_group(q2, plA, pbA, idx_h, bitsel);
        dp_group<FWD>(plB, pbB, allow2f, st_e, st_o, ls, f, a2f);
        // j = 2: dp(gb+2) [A], softmax(gb+3)->B, load(gb+6)->q2
        prod_load<FWD>(rp2, q2, gb + 6, lane);
        softmax_group(q3, plB, pbB, idx_h, bitsel);
        dp_group<FWD>(plA, pbA, allow2f, st_e, st_o, ls, f, a2f);
        // j = 3: dp(gb+3) [B], softmax(gb+4)->A, load(gb+7)->q3
        prod_load<FWD>(rp2, q3, gb + 7, lane);
        softmax_group(q0, plA, pbA, idx_h, bitsel);
        dp_group<FWD>(plB, pbB, allow2f, st_e, st_o, ls, f, a2f);
    }
    // epilogue: groups 20..23 (loads done; q0..q3 hold 20..23; A holds 20)
    softmax_group(q1, plB, pbB, idx_h, bitsel);               // 21
    dp_group<FWD>(plA, pbA, allow2f, st_e, st_o, ls, f, a2f); // dp 20
    softmax_group(q2, plA, pbA, idx_h, bitsel);               // 22
    dp_group<FWD>(plB, pbB, allow2f, st_e, st_o, ls, f, a2f); // dp 21
    softmax_group(q3, plB, pbB, idx_h, bitsel);               // 23
    dp_group<FWD>(plA, pbA, allow2f, st_e, st_o, ls, f, a2f); // dp 22
    dp_group<FWD>(plB, pbB, allow2f, st_e, st_o, ls, f, a2f); // dp 23
}

__global__ __launch_bounds__(64) void zero_kernel(float* o) { *o = 0.0f; }

// 2 waves/block: wv0 = fwd half (t=0..191), wv1 = bwd half (t=383..192). No main-loop
// barriers; one barrier to combine at t=192.
__global__ __launch_bounds__(128) void ctc_fb(const int* __restrict__ labels,
                                              const float* __restrict__ pred,
                                              float* __restrict__ out,
                                              float invB) {
    const int b    = blockIdx.x;
    const int lane = threadIdx.x & 63;
    const int wv   = threadIdx.x >> 6;
    const float2* rp2 = (const float2*)(pred + (size_t)b * Tt * Cc);

    __shared__ float sbe[64], sbo[64];
    __shared__ int   slsb[64];

    // lane i holds label i
    int v = (lane < Ll) ? labels[(size_t)b * Ll + lane] : -1;
    int present = (lane < Ll) && (v != -1);
    int labv = (v < 0) ? 0 : v;
    unsigned long long pm = __ballot(present);
    int len = __popcll(pm);
    int idx_h  = labv >> 1;
    int bitsel = labv & 1;
    int lab_p = __shfl(labv, (lane - 1) & 63, 64);
    int lab_n = __shfl(labv, (lane + 1) & 63, 64);

    float st_e, st_o = 0.0f, f = 1.0f, a2f, allow2f;
    int   ls = 0;

    if (wv == 0) {            // fwd DP: virtual pre-start state at lane 0
        allow2f = (lane >= 1 && labv != lab_p) ? 1.0f : 0.0f;
        st_e = (lane == 0) ? 1.0f : 0.0f;
        a2f = allow2f;
        run_half<true>(rp2, lane, idx_h, bitsel, allow2f, st_e, st_o, ls, f, a2f);
    } else {                  // bwd DP: virtual post-end state at lane == len
        allow2f = (labv != lab_n) ? 1.0f : 0.0f;
        st_e = (lane == len) ? 1.0f : 0.0f;
        a2f = allow2f;
        run_half<false>(rp2, lane, idx_h, bitsel, allow2f, st_e, st_o, ls, f, a2f);
        sbe[lane]  = st_e;
        sbo[lane]  = st_o;
        slsb[lane] = ls;
    }
    __syncthreads();

    if (wv == 0) {
        // transition half-step (no emission) to meet beta at t = 192
        float sh  = shup1(st_o);
        int   lsu = dppi<0x138>(ls);
        float fup = exp2i(lsu - ls);
        float Ae = fmaf(fup, sh, st_e);
        float Ao = fmaf(allow2f * fup, sh, st_e + st_o);
        // combine in log2 domain with integer exponents restored
        float be = sbe[lane], bo = sbo[lane];
        float base = (float)(ls + slsb[lane]);
        float l1 = (Ae > 0.0f && be > 0.0f) ? __log2f(Ae) + __log2f(be) + base : LNEG;
        float l2 = (Ao > 0.0f && bo > 0.0f) ? __log2f(Ao) + __log2f(bo) + base : LNEG;
        float mm = fmaxf(l1, l2);
#pragma unroll
        for (int off = 32; off >= 1; off >>= 1) mm = fmaxf(mm, __shfl_xor(mm, off, 64));
        float ss = exp2f(l1 - mm) + exp2f(l2 - mm);
#pragma unroll
        for (int off = 32; off >= 1; off >>= 1) ss += __shfl_xor(ss, off, 64);
        if (lane == 0) {
            float ll = (mm + __log2f(ss)) * LN2;
            atomicAdd(out, -ll * invB);
        }
    }
}

extern "C" void kernel_launch(void* const* d_in, const int* in_sizes, int n_in,
                              void* d_out, int out_size, void* d_ws, size_t ws_size,
                              hipStream_t stream) {
    const int*   labels = (const int*)d_in[0];
    const float* pred   = (const float*)d_in[1];
    float*       out    = (float*)d_out;

    const int B = in_sizes[0] / Ll;  // 1024

    hipLaunchKernelGGL(zero_kernel, dim3(1), dim3(64), 0, stream, out);
    hipLaunchKernelGGL(ctc_fb, dim3(B), dim3(128), 0, stream,
                       labels, pred, out, 1.0f / (float)B);
}